// Round 1
// baseline (1096.727 us; speedup 1.0000x reference)
//
#include <hip/hip_runtime.h>

// Problem constants: B=2, L=2048, D=2048, H=16, DH=128, M=B*L=4096
typedef unsigned short u16;
typedef __bf16 bfrag __attribute__((ext_vector_type(8)));   // 8 bf16 = 4 VGPRs (MFMA A/B frag)
typedef unsigned short usx8 __attribute__((ext_vector_type(8)));
typedef float f32x4 __attribute__((ext_vector_type(4)));    // MFMA C/D frag

#define MFMA16 __builtin_amdgcn_mfma_f32_16x16x32_bf16

__device__ __forceinline__ u16 f2bf(float f) {
  unsigned u = __builtin_bit_cast(unsigned, f);
  u += 0x7fffu + ((u >> 16) & 1u);          // RNE
  return (u16)(u >> 16);
}
__device__ __forceinline__ float bf2f(u16 s) {
  return __builtin_bit_cast(float, (unsigned)s << 16);
}
__device__ __forceinline__ void splitf(float x, u16 &h, u16 &l) {
  h = f2bf(x);
  l = f2bf(x - bf2f(h));                    // exact residual (Sterbenz), then RNE
}

// ---------------------------------------------------------------------------
// Generic GEMM: C[M=4096][N=2048] = A[M][K=2048] @ W[N][K]^T + bias[N]
// AMODE: 0 = A is fp32 global, 1 = A is bf16(u16) global
// SPLIT: hi/lo bf16 decomposition of both A and W (3 MFMA products) -> ~fp32 acc
// OUTM : 0 = fp32 to [B,H,L,DH]   (Q/K projections)
//        1 = bf16 to [B,H,DH,L]   (V projection, pre-transposed for PV)
//        2 = fp32 row-major [M][N] (final output projection)
// Tile: 128x128, BK=32, 4 waves in 2x2, each wave 64x64 via 4x4 mfma 16x16x32.
// ---------------------------------------------------------------------------
template<int AMODE, bool SPLIT, int OUTM>
__global__ __launch_bounds__(256, 2)
void gemm_k(const void* __restrict__ Ap, const float* __restrict__ W,
            const float* __restrict__ bias, void* __restrict__ outp)
{
  // +8 pad: row stride 40 u16 = 80 B (16B-aligned rows, 2-way bank alias = free)
  __shared__ u16 Ahi[128][40];
  __shared__ u16 Whi[128][40];
  __shared__ u16 Alo[SPLIT ? 128 : 1][40];
  __shared__ u16 Wlo[SPLIT ? 128 : 1][40];

  const int tid = threadIdx.x, wave = tid >> 6, lane = tid & 63;
  const int quad = lane >> 4, l16 = lane & 15;
  const int bm = blockIdx.y * 128, bn = blockIdx.x * 128;
  const int wm = (wave >> 1) * 64, wn = (wave & 1) * 64;

  f32x4 acc[4][4] = {};

  for (int k0 = 0; k0 < 2048; k0 += 32) {
    __syncthreads();
    // stage 128x32 tiles of A and W (fp32 -> bf16 hi/lo), 4 float4 each per thread
#pragma unroll
    for (int it = 0; it < 4; ++it) {
      int idx = tid + it * 256;
      int row = idx >> 3, c4 = (idx & 7) << 2;
      {
        float4 wv = *(const float4*)(W + (size_t)(bn + row) * 2048 + k0 + c4);
        ushort4 h, l;
        splitf(wv.x, h.x, l.x); splitf(wv.y, h.y, l.y);
        splitf(wv.z, h.z, l.z); splitf(wv.w, h.w, l.w);
        *(ushort4*)&Whi[row][c4] = h;
        if constexpr (SPLIT) *(ushort4*)&Wlo[row][c4] = l;
      }
      if constexpr (AMODE == 0) {
        const float* A = (const float*)Ap;
        float4 av = *(const float4*)(A + (size_t)(bm + row) * 2048 + k0 + c4);
        ushort4 h, l;
        splitf(av.x, h.x, l.x); splitf(av.y, h.y, l.y);
        splitf(av.z, h.z, l.z); splitf(av.w, h.w, l.w);
        *(ushort4*)&Ahi[row][c4] = h;
        if constexpr (SPLIT) *(ushort4*)&Alo[row][c4] = l;
      } else {
        const u16* A = (const u16*)Ap;
        *(ushort4*)&Ahi[row][c4] =
            *(const ushort4*)(A + (size_t)(bm + row) * 2048 + k0 + c4);
      }
    }
    __syncthreads();

    bfrag af[4], bfv[4];
#pragma unroll
    for (int i = 0; i < 4; ++i)
      af[i] = *(const bfrag*)&Ahi[wm + i * 16 + l16][quad * 8];
#pragma unroll
    for (int i = 0; i < 4; ++i)
      bfv[i] = *(const bfrag*)&Whi[wn + i * 16 + l16][quad * 8];

    if constexpr (SPLIT) {
      bfrag al[4], bl[4];
#pragma unroll
      for (int i = 0; i < 4; ++i)
        al[i] = *(const bfrag*)&Alo[wm + i * 16 + l16][quad * 8];
#pragma unroll
      for (int i = 0; i < 4; ++i)
        bl[i] = *(const bfrag*)&Wlo[wn + i * 16 + l16][quad * 8];
#pragma unroll
      for (int mi = 0; mi < 4; ++mi)
#pragma unroll
        for (int ni = 0; ni < 4; ++ni) {
          acc[mi][ni] = MFMA16(af[mi], bfv[ni], acc[mi][ni], 0, 0, 0);
          acc[mi][ni] = MFMA16(af[mi], bl[ni],  acc[mi][ni], 0, 0, 0);
          acc[mi][ni] = MFMA16(al[mi], bfv[ni], acc[mi][ni], 0, 0, 0);
        }
    } else {
#pragma unroll
      for (int mi = 0; mi < 4; ++mi)
#pragma unroll
        for (int ni = 0; ni < 4; ++ni)
          acc[mi][ni] = MFMA16(af[mi], bfv[ni], acc[mi][ni], 0, 0, 0);
    }
  }

  // epilogue: C/D layout col=lane&15, row=quad*4+r
#pragma unroll
  for (int ni = 0; ni < 4; ++ni) {
    int n_g = bn + wn + ni * 16 + l16;
    float bv = bias[n_g];
#pragma unroll
    for (int mi = 0; mi < 4; ++mi)
#pragma unroll
      for (int r = 0; r < 4; ++r) {
        int m_g = bm + wm + mi * 16 + quad * 4 + r;
        float v = acc[mi][ni][r] + bv;
        if constexpr (OUTM == 0) {        // fp32 [B,H,L,DH]
          int b = m_g >> 11, l = m_g & 2047, h = n_g >> 7, dh = n_g & 127;
          ((float*)outp)[(((size_t)(b * 16 + h)) * 2048 + l) * 128 + dh] = v;
        } else if constexpr (OUTM == 1) { // bf16 [B,H,DH,L] (transposed V)
          int b = m_g >> 11, l = m_g & 2047, h = n_g >> 7, dh = n_g & 127;
          ((u16*)outp)[(((size_t)(b * 16 + h)) * 128 + dh) * 2048 + l] = f2bf(v);
        } else {                          // fp32 [M][N] == [B,L,D]
          ((float*)outp)[(size_t)m_g * 2048 + n_g] = v;
        }
      }
  }
}

// ---------------------------------------------------------------------------
// Flash attention (causal), faithful to source: scores = (q.k) * sqrt(128),
// masked entries get -1e7 (exp underflows to exactly 0 in fp32, matching ref).
// Block: 128 Q rows (4 waves x 32 rows), KV tiles of 64.
// Q/K path uses hi/lo split bf16 (3 MFMA products) for score precision.
// ---------------------------------------------------------------------------
__global__ __launch_bounds__(256, 2)
void attn_k(const float* __restrict__ qh, const float* __restrict__ kh,
            const u16* __restrict__ vT, u16* __restrict__ Ow)
{
  __shared__ u16 Khi[64][136];   // 128 + 8 pad; 272B rows (16B-aligned, 2-way alias)
  __shared__ u16 Klo[64][136];
  __shared__ u16 VT[128][72];    // [dh][kv], 64 + 8 pad
  __shared__ u16 Pm[4][32][72];  // per-wave P tile for C-layout -> A-layout

  const int tid = threadIdx.x, wave = tid >> 6, lane = tid & 63;
  const int quad = lane >> 4, l16 = lane & 15;
  const int qtile = blockIdx.x, bh = blockIdx.y;
  const float* Qb = qh + (size_t)bh * 2048 * 128;
  const float* Kb = kh + (size_t)bh * 2048 * 128;
  const u16*  Vb  = vT + (size_t)bh * 128 * 2048;
  const int qrow0 = qtile * 128 + wave * 32;
  const float SCALE = 11.31370849898476f;   // sqrt(128) — faithful source bug

  // Q fragments (hi/lo), resident for the whole block
  bfrag qhf[2][4], qlf[2][4];
#pragma unroll
  for (int t = 0; t < 2; ++t)
#pragma unroll
    for (int f = 0; f < 4; ++f) {
      const float* p = Qb + (size_t)(qrow0 + t * 16 + l16) * 128 + f * 32 + quad * 8;
      float4 x0 = *(const float4*)p;
      float4 x1 = *(const float4*)(p + 4);
      float xs[8] = {x0.x, x0.y, x0.z, x0.w, x1.x, x1.y, x1.z, x1.w};
      usx8 uh, ul;
#pragma unroll
      for (int j = 0; j < 8; ++j) {
        u16 hh, ll; splitf(xs[j], hh, ll);
        uh[j] = hh; ul[j] = ll;
      }
      qhf[t][f] = __builtin_bit_cast(bfrag, uh);
      qlf[t][f] = __builtin_bit_cast(bfrag, ul);
    }

  float mprev[2][4], lsum[2][4];
  f32x4 o[2][8] = {};
#pragma unroll
  for (int t = 0; t < 2; ++t)
#pragma unroll
    for (int r = 0; r < 4; ++r) { mprev[t][r] = -3e38f; lsum[t][r] = 0.f; }

  const int nkv = 2 * (qtile + 1);
  for (int kt = 0; kt < nkv; ++kt) {
    const int kv0 = kt * 64;
    __syncthreads();
    // stage K tile 64x128 fp32 -> hi/lo bf16
#pragma unroll
    for (int it = 0; it < 8; ++it) {
      int idx = tid + it * 256;
      int row = idx >> 5, c4 = (idx & 31) << 2;
      float4 x = *(const float4*)(Kb + (size_t)(kv0 + row) * 128 + c4);
      ushort4 h, l;
      splitf(x.x, h.x, l.x); splitf(x.y, h.y, l.y);
      splitf(x.z, h.z, l.z); splitf(x.w, h.w, l.w);
      *(ushort4*)&Khi[row][c4] = h;
      *(ushort4*)&Klo[row][c4] = l;
    }
    // stage V^T tile 128x64 bf16
#pragma unroll
    for (int it = 0; it < 8; ++it) {
      int idx = tid + it * 256;
      int row = idx >> 4, c4 = (idx & 15) << 2;
      *(ushort4*)&VT[row][c4] = *(const ushort4*)(Vb + (size_t)row * 2048 + kv0 + c4);
    }
    __syncthreads();

    // S = Q K^T (split: hh + hl + lh)
    f32x4 s[2][4] = {};
#pragma unroll
    for (int f = 0; f < 4; ++f)
#pragma unroll
      for (int c = 0; c < 4; ++c) {
        bfrag kf = *(const bfrag*)&Khi[c * 16 + l16][f * 32 + quad * 8];
        bfrag kl = *(const bfrag*)&Klo[c * 16 + l16][f * 32 + quad * 8];
#pragma unroll
        for (int t = 0; t < 2; ++t) {
          s[t][c] = MFMA16(qhf[t][f], kf, s[t][c], 0, 0, 0);
          s[t][c] = MFMA16(qhf[t][f], kl, s[t][c], 0, 0, 0);
          s[t][c] = MFMA16(qlf[t][f], kf, s[t][c], 0, 0, 0);
        }
      }

    // online softmax; rows of a 16-tile live across the 16 lanes of a quad
#pragma unroll
    for (int t = 0; t < 2; ++t)
#pragma unroll
      for (int r = 0; r < 4; ++r) {
        const int rg = qrow0 + t * 16 + quad * 4 + r;
        float sv[4];
#pragma unroll
        for (int c = 0; c < 4; ++c) {
          int cg = kv0 + c * 16 + l16;
          sv[c] = (cg <= rg) ? s[t][c][r] * SCALE : -1e7f;
        }
        float mx = fmaxf(fmaxf(sv[0], sv[1]), fmaxf(sv[2], sv[3]));
#pragma unroll
        for (int off = 1; off < 16; off <<= 1) mx = fmaxf(mx, __shfl_xor(mx, off));
        float mnew = fmaxf(mprev[t][r], mx);
        float al = __expf(mprev[t][r] - mnew);
        float ps = 0.f;
#pragma unroll
        for (int c = 0; c < 4; ++c) { sv[c] = __expf(sv[c] - mnew); ps += sv[c]; }
#pragma unroll
        for (int off = 1; off < 16; off <<= 1) ps += __shfl_xor(ps, off);
        lsum[t][r] = lsum[t][r] * al + ps;
        mprev[t][r] = mnew;
#pragma unroll
        for (int d = 0; d < 8; ++d) o[t][d][r] *= al;
#pragma unroll
        for (int c = 0; c < 4; ++c)
          Pm[wave][t * 16 + quad * 4 + r][c * 16 + l16] = f2bf(sv[c]);
      }
    __syncthreads();

    // O += P @ V  (P: A-layout from LDS; V^T: B-layout [n=dh][k=kv])
#pragma unroll
    for (int k2 = 0; k2 < 2; ++k2) {
      bfrag pf0 = *(const bfrag*)&Pm[wave][l16][k2 * 32 + quad * 8];
      bfrag pf1 = *(const bfrag*)&Pm[wave][16 + l16][k2 * 32 + quad * 8];
#pragma unroll
      for (int d = 0; d < 8; ++d) {
        bfrag vf = *(const bfrag*)&VT[d * 16 + l16][k2 * 32 + quad * 8];
        o[0][d] = MFMA16(pf0, vf, o[0][d], 0, 0, 0);
        o[1][d] = MFMA16(pf1, vf, o[1][d], 0, 0, 0);
      }
    }
  }

  // epilogue: normalize, store bf16 to O[B,L,D]
  const int b = bh >> 4, h = bh & 15;
#pragma unroll
  for (int t = 0; t < 2; ++t)
#pragma unroll
    for (int r = 0; r < 4; ++r) {
      int rg = qrow0 + t * 16 + quad * 4 + r;
      float inv = 1.f / lsum[t][r];
#pragma unroll
      for (int d = 0; d < 8; ++d)
        Ow[((size_t)(b * 2048 + rg)) * 2048 + h * 128 + d * 16 + l16] =
            f2bf(o[t][d][r] * inv);
    }
}

// ---------------------------------------------------------------------------
extern "C" void kernel_launch(void* const* d_in, const int* in_sizes, int n_in,
                              void* d_out, int out_size, void* d_ws, size_t ws_size,
                              hipStream_t stream) {
  const float* q  = (const float*)d_in[0];
  const float* k  = (const float*)d_in[1];
  const float* v  = (const float*)d_in[2];
  const float* Wq = (const float*)d_in[3];
  const float* bq = (const float*)d_in[4];
  const float* Wk = (const float*)d_in[5];
  const float* bk = (const float*)d_in[6];
  const float* Wv = (const float*)d_in[7];
  const float* bv = (const float*)d_in[8];
  const float* Wo = (const float*)d_in[9];
  const float* bo = (const float*)d_in[10];

  // workspace: qh fp32 (32MB) | kh fp32 (32MB) | vT bf16 (16MB) | O bf16 (16MB)
  float* qh = (float*)d_ws;
  float* kh = qh + 8388608;
  u16*   vT = (u16*)(kh + 8388608);
  u16*   Ow = vT + 8388608;

  dim3 blk(256);
  dim3 gg(16, 32);   // N/128, M/128
  gemm_k<0, true,  0><<<gg, blk, 0, stream>>>(q, Wq, bq, qh);
  gemm_k<0, true,  0><<<gg, blk, 0, stream>>>(k, Wk, bk, kh);
  gemm_k<0, false, 1><<<gg, blk, 0, stream>>>(v, Wv, bv, vT);
  attn_k<<<dim3(16, 32), blk, 0, stream>>>(qh, kh, vT, Ow);
  gemm_k<1, false, 2><<<gg, blk, 0, stream>>>(Ow, Wo, bo, d_out);
}